// Round 1
// baseline (502.855 us; speedup 1.0000x reference)
//
#include <hip/hip_runtime.h>
#include <hip/hip_bf16.h>

// Sizes (fixed by the problem)
#define NN 512
#define DD 128
#define EE 16384
#define K3 384

typedef __attribute__((ext_vector_type(8))) short bf16x8;
typedef __attribute__((ext_vector_type(4))) short bf16x4;
typedef __attribute__((ext_vector_type(4))) float f32x4;

__device__ inline short f2bf(float f) {
    union { __hip_bfloat16 h; short s; } u;
    u.h = __float2bfloat16(f);
    return u.s;
}

// ---------------- tiny prep kernels ----------------

__global__ void k_zero(float* __restrict__ At) {
    At[blockIdx.x * 256 + threadIdx.x] = 0.0f;
}

// Build At[dst][src] += 1.  Robust to the harness passing edge_index as
// int32 (doc'd) or raw int64 (reference dtype): for int64 little-endian,
// every odd 32-bit word in the first half is 0 (values < 512).
__global__ void k_edges(const int* __restrict__ ei, float* __restrict__ At) {
    __shared__ int flag;
    if (threadIdx.x == 0) flag = 0;
    __syncthreads();
    int any = 0;
    for (int i = threadIdx.x; i < EE; i += blockDim.x) any |= ei[2 * i + 1];
    if (any) atomicOr(&flag, 1);
    __syncthreads();
    const bool is32 = (flag != 0);
    for (int e = threadIdx.x; e < EE; e += blockDim.x) {
        int src, dst;
        if (is32) { src = ei[e];     dst = ei[EE + e]; }
        else      { src = ei[2 * e]; dst = ei[2 * (EE + e)]; }
        atomicAdd(&At[dst * NN + src], 1.0f);
    }
}

// Wt[n][kk] = bf16(W[kk][n])  (transpose+cast, so K is contiguous for MFMA B-op)
__global__ void k_wt(const float* __restrict__ W, short* __restrict__ Wt) {
    int t = blockIdx.x * 256 + threadIdx.x;     // t = kk*128 + n
    int kk = t >> 7, n = t & 127;
    Wt[n * K3 + kk] = f2bf(W[t]);
}

// ---------------- unified aggregation GEMM ----------------
// C[r,d] = sum_k At[a0+r, k] * B[k, d], 128x128 tile, K=512.
// Blocks 0..2047:  X1[i, jt*128+r, d] = sum_k At[j,k] X[i,k,d]
// Blocks 2048..:   X2[it*128+r, j, d] = sum_k At[i,k] X[k,j,d]
__global__ __launch_bounds__(256) void k_agg(const float* __restrict__ X,
                                             const float* __restrict__ At,
                                             short* __restrict__ X1b,
                                             short* __restrict__ X2b) {
    __shared__ short As[128 * 72];   // [r][k], k-contig, pad 64->72
    __shared__ short Bs[128 * 72];   // [d][k], k-contig (transposed on stage)

    const int tid  = threadIdx.x;
    const int lane = tid & 63;
    const int wv   = tid >> 6;
    const int wr   = (wv >> 1) * 64;
    const int wc   = (wv & 1) * 64;
    const int lm   = lane & 15;
    const int lq   = lane >> 4;

    int a0, Bbase, Bks, Cbase, Crs;
    short* Cp;
    const int bidx = blockIdx.x;
    if (bidx < 2048) {
        int i = bidx >> 2, jt = bidx & 3;
        a0 = jt * 128; Bbase = i * 65536; Bks = 128;
        Cbase = i * 65536 + jt * 16384; Crs = 128; Cp = X1b;
    } else {
        int bb = bidx - 2048;
        int j = bb >> 2, it = bb & 3;
        a0 = it * 128; Bbase = j * 128; Bks = 65536;
        Cbase = it * 8388608 + j * 128; Crs = 65536; Cp = X2b;
    }

    f32x4 acc[4][4] = {};

    const int d  = tid & 127;
    const int kh = tid >> 7;

    for (int kb = 0; kb < 8; ++kb) {
        const int k0 = kb * 64;
        // --- stage A panel: At rows [a0, a0+128), cols [k0, k0+64), fp32 -> bf16
        #pragma unroll
        for (int it8 = 0; it8 < 8; ++it8) {
            int g = tid + it8 * 256;
            int r = g >> 4, kq = (g & 15) * 4;
            float4 v = *(const float4*)&At[(a0 + r) * 512 + k0 + kq];
            bf16x4 p; p[0] = f2bf(v.x); p[1] = f2bf(v.y); p[2] = f2bf(v.z); p[3] = f2bf(v.w);
            *(bf16x4*)&As[r * 72 + kq] = p;
        }
        // --- stage B panel transposed: Bs[d][k] = X[Bbase + k*Bks + d]
        #pragma unroll
        for (int gi = 0; gi < 4; ++gi) {
            int kg = kh * 4 + gi;           // 0..7
            bf16x8 p;
            #pragma unroll
            for (int j = 0; j < 8; ++j)
                p[j] = f2bf(X[Bbase + (k0 + kg * 8 + j) * Bks + d]);
            *(bf16x8*)&Bs[d * 72 + kg * 8] = p;
        }
        __syncthreads();
        #pragma unroll
        for (int ks = 0; ks < 2; ++ks) {
            bf16x8 af[4], bfr[4];
            #pragma unroll
            for (int mf = 0; mf < 4; ++mf)
                af[mf] = *(const bf16x8*)&As[(wr + mf * 16 + lm) * 72 + ks * 32 + lq * 8];
            #pragma unroll
            for (int nf = 0; nf < 4; ++nf)
                bfr[nf] = *(const bf16x8*)&Bs[(wc + nf * 16 + lm) * 72 + ks * 32 + lq * 8];
            #pragma unroll
            for (int mf = 0; mf < 4; ++mf)
                #pragma unroll
                for (int nf = 0; nf < 4; ++nf)
                    acc[mf][nf] = __builtin_amdgcn_mfma_f32_16x16x32_bf16(
                        af[mf], bfr[nf], acc[mf][nf], 0, 0, 0);
        }
        __syncthreads();
    }

    // epilogue: C/D layout col=lane&15, row=(lane>>4)*4+reg  [m89-verified]
    #pragma unroll
    for (int mf = 0; mf < 4; ++mf)
        #pragma unroll
        for (int nf = 0; nf < 4; ++nf)
            #pragma unroll
            for (int r = 0; r < 4; ++r) {
                int row = wr + mf * 16 + lq * 4 + r;
                int col = wc + nf * 16 + lm;
                Cp[Cbase + row * Crs + col] = f2bf(acc[mf][nf][r]);
            }
}

// ---------------- final fused concat-GEMM ----------------
// out[m, n] = sum_s sum_d act_s[m, d] * W[s*128+d, n] + b[n]
// act_0 = X (fp32), act_1 = X1b, act_2 = X2b.  M=262144, N=128, K=384.
__global__ __launch_bounds__(256) void k_final(const float* __restrict__ X,
                                               const short* __restrict__ X1b,
                                               const short* __restrict__ X2b,
                                               const short* __restrict__ Wt,
                                               const float* __restrict__ bias,
                                               float* __restrict__ out) {
    __shared__ short As[128 * 72];   // activations [r][k]
    __shared__ short Ws[128 * 72];   // weights [n][k]

    const int tid  = threadIdx.x;
    const int lane = tid & 63;
    const int wv   = tid >> 6;
    const int wr   = (wv >> 1) * 64;
    const int wc   = (wv & 1) * 64;
    const int lm   = lane & 15;
    const int lq   = lane >> 4;
    const int m0   = blockIdx.x * 128;

    f32x4 acc[4][4] = {};

    for (int ph = 0; ph < 6; ++ph) {
        const int s = ph >> 1, h = ph & 1;
        if (s == 0) {
            #pragma unroll
            for (int it8 = 0; it8 < 8; ++it8) {
                int g = tid + it8 * 256;
                int r = g >> 4, kq = (g & 15) * 4;
                float4 v = *(const float4*)&X[(m0 + r) * 128 + h * 64 + kq];
                bf16x4 p; p[0] = f2bf(v.x); p[1] = f2bf(v.y); p[2] = f2bf(v.z); p[3] = f2bf(v.w);
                *(bf16x4*)&As[r * 72 + kq] = p;
            }
        } else {
            const short* src = (s == 1) ? X1b : X2b;
            #pragma unroll
            for (int it4 = 0; it4 < 4; ++it4) {
                int g = tid + it4 * 256;
                int r = g >> 3, ko = (g & 7) * 8;
                *(bf16x8*)&As[r * 72 + ko] =
                    *(const bf16x8*)&src[(m0 + r) * 128 + h * 64 + ko];
            }
        }
        #pragma unroll
        for (int it4 = 0; it4 < 4; ++it4) {
            int g = tid + it4 * 256;
            int n = g >> 3, ko = (g & 7) * 8;
            *(bf16x8*)&Ws[n * 72 + ko] =
                *(const bf16x8*)&Wt[n * K3 + s * 128 + h * 64 + ko];
        }
        __syncthreads();
        #pragma unroll
        for (int ks = 0; ks < 2; ++ks) {
            bf16x8 af[4], bfr[4];
            #pragma unroll
            for (int mf = 0; mf < 4; ++mf)
                af[mf] = *(const bf16x8*)&As[(wr + mf * 16 + lm) * 72 + ks * 32 + lq * 8];
            #pragma unroll
            for (int nf = 0; nf < 4; ++nf)
                bfr[nf] = *(const bf16x8*)&Ws[(wc + nf * 16 + lm) * 72 + ks * 32 + lq * 8];
            #pragma unroll
            for (int mf = 0; mf < 4; ++mf)
                #pragma unroll
                for (int nf = 0; nf < 4; ++nf)
                    acc[mf][nf] = __builtin_amdgcn_mfma_f32_16x16x32_bf16(
                        af[mf], bfr[nf], acc[mf][nf], 0, 0, 0);
        }
        __syncthreads();
    }

    #pragma unroll
    for (int nf = 0; nf < 4; ++nf) {
        float bv = bias[wc + nf * 16 + lm];
        #pragma unroll
        for (int mf = 0; mf < 4; ++mf)
            #pragma unroll
            for (int r = 0; r < 4; ++r) {
                int row = m0 + wr + mf * 16 + lq * 4 + r;
                int col = wc + nf * 16 + lm;
                out[row * 128 + col] = acc[mf][nf][r] + bv;
            }
    }
}

extern "C" void kernel_launch(void* const* d_in, const int* in_sizes, int n_in,
                              void* d_out, int out_size, void* d_ws, size_t ws_size,
                              hipStream_t stream) {
    const float* X  = (const float*)d_in[0];
    const int*   ei = (const int*)d_in[1];
    const float* W  = (const float*)d_in[2];
    const float* b  = (const float*)d_in[3];
    float* out = (float*)d_out;

    // workspace layout (needs 130 MiB):
    //   [0, 1MiB)        At fp32 [512][512]
    //   [1MiB, +96KiB)   Wt bf16 [128][384]
    //   [2MiB, +64MiB)   X1b bf16 [512][512][128]
    //   [66MiB, +64MiB)  X2b bf16
    float* At  = (float*)d_ws;
    short* Wt  = (short*)((char*)d_ws + (size_t)(1u << 20));
    short* X1b = (short*)((char*)d_ws + (size_t)(2u << 20));
    short* X2b = (short*)((char*)d_ws + (size_t)(2u << 20) + (size_t)(64u << 20));

    k_zero <<<1024, 256, 0, stream>>>(At);
    k_edges<<<1, 1024, 0, stream>>>(ei, At);
    k_wt   <<<192, 256, 0, stream>>>(W, Wt);
    k_agg  <<<4096, 256, 0, stream>>>(X, At, X1b, X2b);
    k_final<<<2048, 256, 0, stream>>>(X, X1b, X2b, Wt, b, out);
}